// Round 12
// baseline (56.005 us; speedup 1.0000x reference)
//
#include <hip/hip_runtime.h>
#include <hip/hip_bf16.h>

#define BSZ   4096
#define DIM   512
#define NROW  8192
#define NBLK_NORM (BSZ / 4)
#define INV_T 14.285714285714285f

typedef float f32x4 __attribute__((ext_vector_type(4)));

#define GLOAD_LDS16(gp, lp) __builtin_amdgcn_global_load_lds( \
    (const __attribute__((address_space(1))) unsigned int*)(const void*)(gp), \
    (__attribute__((address_space(3))) unsigned int*)(void*)(lp), 16, 0, 0)

// ---------------------------------------------------------------------------
// Kernel 1: row-normalize z1,z2 -> fp8 e4m3 F[8192][512]; per-block positive-
// pair dot partials -> posbuf (exact fp32); zeroes rowsum (8/block = all 8192).
// ---------------------------------------------------------------------------
__device__ __forceinline__ unsigned pack_fp8x4(float4 v, float s) {
    int w = 0;
    w = __builtin_amdgcn_cvt_pk_fp8_f32(v.x * s, v.y * s, w, false);
    w = __builtin_amdgcn_cvt_pk_fp8_f32(v.z * s, v.w * s, w, true);
    return (unsigned)w;
}

__global__ __launch_bounds__(256) void nt_norm(const float* __restrict__ z1,
                                               const float* __restrict__ z2,
                                               unsigned char* __restrict__ F,
                                               float* __restrict__ posbuf,
                                               float* __restrict__ rowsum) {
    __shared__ float pd[4];
    const int wid  = threadIdx.x >> 6;
    const int lane = threadIdx.x & 63;
    const int row  = blockIdx.x * 4 + wid;          // 0..4095

    if (threadIdx.x < 8) rowsum[blockIdx.x * 8 + threadIdx.x] = 0.0f;

    const float4* a4 = (const float4*)(z1 + (size_t)row * DIM);
    const float4* b4 = (const float4*)(z2 + (size_t)row * DIM);
    float4 a0 = a4[lane], a1 = a4[64 + lane];
    float4 b0 = b4[lane], b1 = b4[64 + lane];

    float s1 = a0.x*a0.x + a0.y*a0.y + a0.z*a0.z + a0.w*a0.w
             + a1.x*a1.x + a1.y*a1.y + a1.z*a1.z + a1.w*a1.w;
    float s2 = b0.x*b0.x + b0.y*b0.y + b0.z*b0.z + b0.w*b0.w
             + b1.x*b1.x + b1.y*b1.y + b1.z*b1.z + b1.w*b1.w;
    float d  = a0.x*b0.x + a0.y*b0.y + a0.z*b0.z + a0.w*b0.w
             + a1.x*b1.x + a1.y*b1.y + a1.z*b1.z + a1.w*b1.w;

    #pragma unroll
    for (int off = 32; off; off >>= 1) {
        s1 += __shfl_xor(s1, off);
        s2 += __shfl_xor(s2, off);
        d  += __shfl_xor(d,  off);
    }

    const float inv1 = 1.0f / fmaxf(sqrtf(s1), 1e-12f);
    const float inv2 = 1.0f / fmaxf(sqrtf(s2), 1e-12f);

    unsigned char* F1 = F + (size_t)row * DIM;
    unsigned char* F2 = F + (size_t)(BSZ + row) * DIM;
    *(unsigned*)(F1 + lane * 4)       = pack_fp8x4(a0, inv1);
    *(unsigned*)(F1 + 256 + lane * 4) = pack_fp8x4(a1, inv1);
    *(unsigned*)(F2 + lane * 4)       = pack_fp8x4(b0, inv2);
    *(unsigned*)(F2 + 256 + lane * 4) = pack_fp8x4(b1, inv2);

    if (lane == 0) pd[wid] = d * inv1 * inv2;
    __syncthreads();
    if (threadIdx.x == 0)
        posbuf[blockIdx.x] = pd[0] + pd[1] + pd[2] + pd[3];
}

// ---------------------------------------------------------------------------
// Kernel 2: upper-tri 128x128 tile pairs of S = F F^T, fp8 16x16x32 MFMA.
// BK=64 B, kt=8, double-buffered at 32 KB LDS + counted-vmcnt depth-1
// prefetch (R11, verified). NEW: T5 s_setprio(1) around the MFMA cluster
// (counted-vmcnt gives the wave role-split T5 needs — m218b), and the two
// dead tail barriers (kt=6,7: no subsequent stage to protect) removed.
// 16B-granule swizzle slot^=(row>>1)&3 via pre-swizzled source (rule #21);
// super-tile + bijective XCD block order (verified R4+). Epilogue = R7.
// ---------------------------------------------------------------------------
__device__ __forceinline__ void stage64(const unsigned char* __restrict__ Ag,
                                        const unsigned char* __restrict__ Bg,
                                        unsigned char* Asb, unsigned char* Bsb,
                                        int kt, int tid) {
    #pragma unroll
    for (int ch = 0; ch < 2; ++ch) {
        const int i  = ch * 256 + tid;   // 16B chunk id, 0..511
        const int rr = i >> 2;           // tile row 0..127
        const int sl = i & 3;            // dest 16B slot within 64B row
        const int sg = sl ^ ((rr >> 1) & 3);        // inverse-swizzled src slot
        const size_t go = (size_t)rr * DIM + kt * 64 + sg * 16;
        GLOAD_LDS16(Ag + go, Asb + i * 16);         // linear dest (rule #21)
        GLOAD_LDS16(Bg + go, Bsb + i * 16);
    }
}

__global__ __launch_bounds__(256, 4) void simexp(const unsigned char* __restrict__ F,
                                                 float* __restrict__ rowsum) {
    __shared__ __align__(16) unsigned char As[2][128 * 64];   // 16 KB
    __shared__ __align__(16) unsigned char Bs[2][128 * 64];   // 16 KB

    // ---- block id -> (r,c), super-tile order + bijective XCD swizzle ----
    int L = (blockIdx.x & 7) * 260 + (blockIdx.x >> 3);
    int rem = L, s_r = 0;
    for (; s_r < 8; ++s_r) {
        const int rowsz = 36 + 64 * (7 - s_r);
        if (rem < rowsz) break;
        rem -= rowsz;
    }
    int s_c, lr, lc;
    if (rem < 36) {              // diagonal super-tile, triangular 8x8
        s_c = s_r;
        lr = 0;
        while (rem >= 8 - lr) { rem -= 8 - lr; ++lr; }
        lc = lr + rem;
    } else {                     // off-diagonal super-tiles
        rem -= 36;
        s_c = s_r + 1 + (rem >> 6);
        const int j = rem & 63;
        lr = j >> 3; lc = j & 7;
    }
    const int r = s_r * 8 + lr;
    const int c = s_c * 8 + lc;

    const int tid  = threadIdx.x;
    const int wid  = tid >> 6;
    const int lane = tid & 63;
    const int wr   = wid >> 1;            // wave row (0..1) -> 64 rows
    const int wc   = wid & 1;             // wave col (0..1) -> 64 cols
    const size_t row0 = (size_t)r * 128;
    const size_t col0 = (size_t)c * 128;
    const unsigned char* Abase = F + row0 * DIM;
    const unsigned char* Bbase = F + col0 * DIM;

    f32x4 acc[4][4] = {};

    const int rlo = lane & 15;            // fragment row within 16
    const int g8  = (lane >> 4) * 8;      // k-byte base for this lane group
    const int b8  = g8 & 8;               // byte-in-granule

    // prologue: stage K-tiles 0 and 1 (4 loads each per thread)
    stage64(Abase, Bbase, As[0], Bs[0], 0, tid);
    stage64(Abase, Bbase, As[1], Bs[1], 1, tid);

    for (int kt = 0; kt < 8; ++kt) {
        const int cur = kt & 1;
        // wait own 4 loads of tile kt (tile kt+1's 4 remain in flight)
        if (kt < 7) asm volatile("s_waitcnt vmcnt(4)" ::: "memory");
        else        asm volatile("s_waitcnt vmcnt(0)" ::: "memory");
        __builtin_amdgcn_s_barrier();

        const unsigned char* Ac = As[cur];
        const unsigned char* Bc = Bs[cur];
        #pragma unroll
        for (int ks = 0; ks < 2; ++ks) {
            const int gran = (ks * 32 + g8) >> 4;   // 16B granule 0..3
            long a[4], b[4];
            #pragma unroll
            for (int n = 0; n < 4; ++n) {
                const int row = wc * 64 + n * 16 + rlo;
                b[n] = *(const long*)(Bc + row * 64 +
                                      ((gran ^ ((row >> 1) & 3)) << 4) + b8);
            }
            #pragma unroll
            for (int m = 0; m < 4; ++m) {
                const int row = wr * 64 + m * 16 + rlo;
                a[m] = *(const long*)(Ac + row * 64 +
                                      ((gran ^ ((row >> 1) & 3)) << 4) + b8);
            }
            __builtin_amdgcn_s_setprio(1);          // T5: favor MFMA cluster
            #pragma unroll
            for (int m = 0; m < 4; ++m)
                #pragma unroll
                for (int n = 0; n < 4; ++n)
                    acc[m][n] = __builtin_amdgcn_mfma_f32_16x16x32_fp8_fp8(
                        a[m], b[n], acc[m][n], 0, 0, 0);
            __builtin_amdgcn_s_setprio(0);
        }

        if (kt < 6) {                      // refill the buffer just freed
            __builtin_amdgcn_s_barrier();  // all waves done reading buf[cur]
            stage64(Abase, Bbase, As[cur], Bs[cur], kt + 2, tid);
        }
        // kt = 6,7: no stage follows -> tail barrier unnecessary
    }

    // epilogue: p = exp((dot-1)/tau); C/D map col=lane&15, row=(lane>>4)*4+j
    float p[4][4][4];
    #pragma unroll
    for (int m = 0; m < 4; ++m)
        #pragma unroll
        for (int n = 0; n < 4; ++n)
            #pragma unroll
            for (int j = 0; j < 4; ++j)
                p[m][n][j] = __expf((acc[m][n][j] - 1.0f) * INV_T);

    #pragma unroll
    for (int m = 0; m < 4; ++m)
        #pragma unroll
        for (int j = 0; j < 4; ++j) {
            float rs = p[m][0][j] + p[m][1][j] + p[m][2][j] + p[m][3][j];
            rs += __shfl_xor(rs, 1);
            rs += __shfl_xor(rs, 2);
            rs += __shfl_xor(rs, 4);
            rs += __shfl_xor(rs, 8);
            if ((lane & 15) == 0) {
                const int grow = (int)row0 + wr * 64 + m * 16 + ((lane >> 4) << 2) + j;
                atomicAdd(&rowsum[grow], rs);
            }
        }

    if (r != c) {
        #pragma unroll
        for (int n = 0; n < 4; ++n) {
            float cs = 0.f;
            #pragma unroll
            for (int m = 0; m < 4; ++m)
                #pragma unroll
                for (int j = 0; j < 4; ++j)
                    cs += p[m][n][j];
            cs += __shfl_xor(cs, 16);
            cs += __shfl_xor(cs, 32);
            if (lane < 16) {
                const int gcol = (int)col0 + wc * 64 + n * 16 + lane;
                atomicAdd(&rowsum[gcol], cs);
            }
        }
    }
}

// ---------------------------------------------------------------------------
// Kernel 3: loss = 1/tau + mean(log E_i) - (sum posbuf)/tau/4096
// ---------------------------------------------------------------------------
__global__ __launch_bounds__(1024) void nt_final(const float* __restrict__ rowsum,
                                                 const float* __restrict__ posbuf,
                                                 float* __restrict__ out) {
    __shared__ float redl[1024];
    __shared__ float redp[1024];
    float s = 0.f, ps = 0.f;
    for (int i = threadIdx.x; i < NROW; i += 1024) s += logf(rowsum[i]);
    for (int i = threadIdx.x; i < NBLK_NORM; i += 1024) ps += posbuf[i];
    redl[threadIdx.x] = s;
    redp[threadIdx.x] = ps;
    __syncthreads();
    for (int off = 512; off; off >>= 1) {
        if (threadIdx.x < off) {
            redl[threadIdx.x] += redl[threadIdx.x + off];
            redp[threadIdx.x] += redp[threadIdx.x + off];
        }
        __syncthreads();
    }
    if (threadIdx.x == 0) {
        out[0] = INV_T + redl[0] / (float)NROW - redp[0] * INV_T / (float)BSZ;
    }
}

extern "C" void kernel_launch(void* const* d_in, const int* in_sizes, int n_in,
                              void* d_out, int out_size, void* d_ws, size_t ws_size,
                              hipStream_t stream) {
    const float* z1 = (const float*)d_in[0];
    const float* z2 = (const float*)d_in[1];
    // d_in[2] (labels) unused by the reference computation

    unsigned char* F = (unsigned char*)d_ws;
    const size_t FBYTES = (size_t)NROW * DIM;   // 4 MiB fp8
    float* rowsum = (float*)((char*)d_ws + FBYTES);
    float* posbuf = rowsum + NROW;

    nt_norm<<<dim3(NBLK_NORM), dim3(256), 0, stream>>>(z1, z2, F, posbuf, rowsum);
    simexp<<<dim3(2080), dim3(256), 0, stream>>>(F, rowsum);
    nt_final<<<dim3(1), dim3(1024), 0, stream>>>(rowsum, posbuf, (float*)d_out);
}

// Round 13
// 52.800 us; speedup vs baseline: 1.0607x; 1.0607x over previous
//
#include <hip/hip_runtime.h>
#include <hip/hip_bf16.h>

#define BSZ   4096
#define DIM   512
#define NROW  8192
#define NBLK_NORM (BSZ / 4)
#define INV_T 14.285714285714285f

typedef float f32x4 __attribute__((ext_vector_type(4)));

#define GLOAD_LDS16(gp, lp) __builtin_amdgcn_global_load_lds( \
    (const __attribute__((address_space(1))) unsigned int*)(const void*)(gp), \
    (__attribute__((address_space(3))) unsigned int*)(void*)(lp), 16, 0, 0)

// ---------------------------------------------------------------------------
// Kernel 1: row-normalize z1,z2 -> fp8 e4m3 F[8192][512]; per-block positive-
// pair dot partials -> posbuf (exact fp32); zeroes rowsum (8/block = all 8192).
// ---------------------------------------------------------------------------
__device__ __forceinline__ unsigned pack_fp8x4(float4 v, float s) {
    int w = 0;
    w = __builtin_amdgcn_cvt_pk_fp8_f32(v.x * s, v.y * s, w, false);
    w = __builtin_amdgcn_cvt_pk_fp8_f32(v.z * s, v.w * s, w, true);
    return (unsigned)w;
}

__global__ __launch_bounds__(256) void nt_norm(const float* __restrict__ z1,
                                               const float* __restrict__ z2,
                                               unsigned char* __restrict__ F,
                                               float* __restrict__ posbuf,
                                               float* __restrict__ rowsum) {
    __shared__ float pd[4];
    const int wid  = threadIdx.x >> 6;
    const int lane = threadIdx.x & 63;
    const int row  = blockIdx.x * 4 + wid;          // 0..4095

    if (threadIdx.x < 8) rowsum[blockIdx.x * 8 + threadIdx.x] = 0.0f;

    const float4* a4 = (const float4*)(z1 + (size_t)row * DIM);
    const float4* b4 = (const float4*)(z2 + (size_t)row * DIM);
    float4 a0 = a4[lane], a1 = a4[64 + lane];
    float4 b0 = b4[lane], b1 = b4[64 + lane];

    float s1 = a0.x*a0.x + a0.y*a0.y + a0.z*a0.z + a0.w*a0.w
             + a1.x*a1.x + a1.y*a1.y + a1.z*a1.z + a1.w*a1.w;
    float s2 = b0.x*b0.x + b0.y*b0.y + b0.z*b0.z + b0.w*b0.w
             + b1.x*b1.x + b1.y*b1.y + b1.z*b1.z + b1.w*b1.w;
    float d  = a0.x*b0.x + a0.y*b0.y + a0.z*b0.z + a0.w*b0.w
             + a1.x*b1.x + a1.y*b1.y + a1.z*b1.z + a1.w*b1.w;

    #pragma unroll
    for (int off = 32; off; off >>= 1) {
        s1 += __shfl_xor(s1, off);
        s2 += __shfl_xor(s2, off);
        d  += __shfl_xor(d,  off);
    }

    const float inv1 = 1.0f / fmaxf(sqrtf(s1), 1e-12f);
    const float inv2 = 1.0f / fmaxf(sqrtf(s2), 1e-12f);

    unsigned char* F1 = F + (size_t)row * DIM;
    unsigned char* F2 = F + (size_t)(BSZ + row) * DIM;
    *(unsigned*)(F1 + lane * 4)       = pack_fp8x4(a0, inv1);
    *(unsigned*)(F1 + 256 + lane * 4) = pack_fp8x4(a1, inv1);
    *(unsigned*)(F2 + lane * 4)       = pack_fp8x4(b0, inv2);
    *(unsigned*)(F2 + 256 + lane * 4) = pack_fp8x4(b1, inv2);

    if (lane == 0) pd[wid] = d * inv1 * inv2;
    __syncthreads();
    if (threadIdx.x == 0)
        posbuf[blockIdx.x] = pd[0] + pd[1] + pd[2] + pd[3];
}

// ---------------------------------------------------------------------------
// Kernel 2: upper-tri 128x128 tile pairs of S = F F^T via NON-scaled fp8
// mfma_f32_16x16x32_fp8_fp8 (2-reg "long" operands -> low VGPR), BK=128 bytes,
// 4 K-steps x 4 sub-chunks. Single-buffered 2-barrier loop (32 KB LDS).
// Staging + 16B XOR swizzle byte^=(row&7)<<4 (rule #21 involution pair);
// super-tile + XCD block order (verified R4+). Best-measured config (R7).
// ---------------------------------------------------------------------------
__device__ __forceinline__ void stage_fp8(const unsigned char* __restrict__ Ag,
                                          const unsigned char* __restrict__ Bg,
                                          unsigned char* Asb, unsigned char* Bsb,
                                          int tid, int wid) {
    #pragma unroll
    for (int ch = 0; ch < 4; ++ch) {
        const int i   = ch * 256 + tid;   // 16B chunk id, 0..1023
        const int rr  = i >> 3;           // tile row 0..127
        const int cb  = (i & 7) * 16;     // dest byte col within 128B row
        const int src = cb ^ ((rr & 7) << 4);          // inverse-swizzled source col
        const int seg = (ch * 256 + wid * 64) * 16;    // wave-uniform dest byte base
        GLOAD_LDS16(Ag + (size_t)rr * DIM + src, Asb + seg);
        GLOAD_LDS16(Bg + (size_t)rr * DIM + src, Bsb + seg);
    }
}

__global__ __launch_bounds__(256, 4) void simexp(const unsigned char* __restrict__ F,
                                                 float* __restrict__ rowsum) {
    __shared__ __align__(16) unsigned char As[128 * 128];   // 16 KB
    __shared__ __align__(16) unsigned char Bs[128 * 128];   // 16 KB

    // ---- block id -> (r,c), super-tile order + bijective XCD swizzle ----
    int L = (blockIdx.x & 7) * 260 + (blockIdx.x >> 3);
    int rem = L, s_r = 0;
    for (; s_r < 8; ++s_r) {
        const int rowsz = 36 + 64 * (7 - s_r);
        if (rem < rowsz) break;
        rem -= rowsz;
    }
    int s_c, lr, lc;
    if (rem < 36) {              // diagonal super-tile, triangular 8x8
        s_c = s_r;
        lr = 0;
        while (rem >= 8 - lr) { rem -= 8 - lr; ++lr; }
        lc = lr + rem;
    } else {                     // off-diagonal super-tiles
        rem -= 36;
        s_c = s_r + 1 + (rem >> 6);
        const int j = rem & 63;
        lr = j >> 3; lc = j & 7;
    }
    const int r = s_r * 8 + lr;
    const int c = s_c * 8 + lc;

    const int tid  = threadIdx.x;
    const int wid  = tid >> 6;
    const int lane = tid & 63;
    const int wr   = wid >> 1;            // wave row (0..1) -> 64 rows
    const int wc   = wid & 1;             // wave col (0..1) -> 64 cols
    const size_t row0 = (size_t)r * 128;
    const size_t col0 = (size_t)c * 128;
    const unsigned char* Abase = F + row0 * DIM;
    const unsigned char* Bbase = F + col0 * DIM;

    f32x4 acc[4][4] = {};

    const int rlo = lane & 15;            // fragment row within 16
    const int g8  = (lane >> 4) * 8;      // k-byte base for this lane group
    const int sw  = (lane & 7) << 4;      // (row&7)<<4 (row%8 == lane%8)

    for (int kt = 0; kt < 4; ++kt) {
        stage_fp8(Abase + kt * 128, Bbase + kt * 128, As, Bs, tid, wid);
        __syncthreads();

        #pragma unroll
        for (int ks = 0; ks < 4; ++ks) {
            const int col = (ks * 32 + g8) ^ sw;   // swizzled k-slot for this lane
            long a[4], b[4];
            #pragma unroll
            for (int n = 0; n < 4; ++n) {
                const int row = wc * 64 + n * 16 + rlo;
                b[n] = *(const long*)(Bs + row * 128 + col);
            }
            #pragma unroll
            for (int m = 0; m < 4; ++m) {
                const int row = wr * 64 + m * 16 + rlo;
                a[m] = *(const long*)(As + row * 128 + col);
            }
            #pragma unroll
            for (int m = 0; m < 4; ++m)
                #pragma unroll
                for (int n = 0; n < 4; ++n)
                    acc[m][n] = __builtin_amdgcn_mfma_f32_16x16x32_fp8_fp8(
                        a[m], b[n], acc[m][n], 0, 0, 0);
        }
        __syncthreads();   // protect LDS from next kt's stage
    }

    // epilogue: p = exp((dot-1)/tau); C/D map col=lane&15, row=(lane>>4)*4+j
    float p[4][4][4];
    #pragma unroll
    for (int m = 0; m < 4; ++m)
        #pragma unroll
        for (int n = 0; n < 4; ++n)
            #pragma unroll
            for (int j = 0; j < 4; ++j)
                p[m][n][j] = __expf((acc[m][n][j] - 1.0f) * INV_T);

    #pragma unroll
    for (int m = 0; m < 4; ++m)
        #pragma unroll
        for (int j = 0; j < 4; ++j) {
            float rs = p[m][0][j] + p[m][1][j] + p[m][2][j] + p[m][3][j];
            rs += __shfl_xor(rs, 1);
            rs += __shfl_xor(rs, 2);
            rs += __shfl_xor(rs, 4);
            rs += __shfl_xor(rs, 8);
            if ((lane & 15) == 0) {
                const int grow = (int)row0 + wr * 64 + m * 16 + ((lane >> 4) << 2) + j;
                atomicAdd(&rowsum[grow], rs);
            }
        }

    if (r != c) {
        #pragma unroll
        for (int n = 0; n < 4; ++n) {
            float cs = 0.f;
            #pragma unroll
            for (int m = 0; m < 4; ++m)
                #pragma unroll
                for (int j = 0; j < 4; ++j)
                    cs += p[m][n][j];
            cs += __shfl_xor(cs, 16);
            cs += __shfl_xor(cs, 32);
            if (lane < 16) {
                const int gcol = (int)col0 + wc * 64 + n * 16 + lane;
                atomicAdd(&rowsum[gcol], cs);
            }
        }
    }
}

// ---------------------------------------------------------------------------
// Kernel 3: loss = 1/tau + mean(log E_i) - (sum posbuf)/tau/4096
// ---------------------------------------------------------------------------
__global__ __launch_bounds__(1024) void nt_final(const float* __restrict__ rowsum,
                                                 const float* __restrict__ posbuf,
                                                 float* __restrict__ out) {
    __shared__ float redl[1024];
    __shared__ float redp[1024];
    float s = 0.f, ps = 0.f;
    for (int i = threadIdx.x; i < NROW; i += 1024) s += logf(rowsum[i]);
    for (int i = threadIdx.x; i < NBLK_NORM; i += 1024) ps += posbuf[i];
    redl[threadIdx.x] = s;
    redp[threadIdx.x] = ps;
    __syncthreads();
    for (int off = 512; off; off >>= 1) {
        if (threadIdx.x < off) {
            redl[threadIdx.x] += redl[threadIdx.x + off];
            redp[threadIdx.x] += redp[threadIdx.x + off];
        }
        __syncthreads();
    }
    if (threadIdx.x == 0) {
        out[0] = INV_T + redl[0] / (float)NROW - redp[0] * INV_T / (float)BSZ;
    }
}

extern "C" void kernel_launch(void* const* d_in, const int* in_sizes, int n_in,
                              void* d_out, int out_size, void* d_ws, size_t ws_size,
                              hipStream_t stream) {
    const float* z1 = (const float*)d_in[0];
    const float* z2 = (const float*)d_in[1];
    // d_in[2] (labels) unused by the reference computation

    unsigned char* F = (unsigned char*)d_ws;
    const size_t FBYTES = (size_t)NROW * DIM;   // 4 MiB fp8
    float* rowsum = (float*)((char*)d_ws + FBYTES);
    float* posbuf = rowsum + NROW;

    nt_norm<<<dim3(NBLK_NORM), dim3(256), 0, stream>>>(z1, z2, F, posbuf, rowsum);
    simexp<<<dim3(2080), dim3(256), 0, stream>>>(F, rowsum);
    nt_final<<<dim3(1), dim3(1024), 0, stream>>>(rowsum, posbuf, (float*)d_out);
}